// Round 7
// baseline (551.211 us; speedup 1.0000x reference)
//
#include <hip/hip_runtime.h>
#include <hip/hip_bf16.h>
#include <math.h>

#define N_NODES 50000
#define N_EDGES 800000
#define C 64
#define EPS_F 1.000001f
#define TWO_N (2 * N_NODES)

// CSR partitioned by edge-block cohort p (see round-4/5 notes: keeps rec[]
// cache-line writers on a fixed 2-XCD set -> no 8x HBM write amplification,
// while NPART=4 keeps gather segments at avg len 4 = one 4-record chunk).
#define NPART 4
#define DEG_SZ (NPART * TWO_N)                          // 400000 bins
#define SCAN_TILE 1024
#define NB_SCAN ((DEG_SZ + SCAN_TILE - 1) / SCAN_TILE)  // 391 tiles
#define DEG_PAD (NB_SCAN * SCAN_TILE)                   // 400384

// Fused build kernel geometry: must satisfy NBLD >= NB_SCAN and
// NBLD <= guaranteed-resident capacity (launch_bounds(256,4) => 4 blocks/CU
// => 1024 resident; 512 leaves 2x margin so the grid barriers cannot hang).
#define NBLD 512
#define BSTRIDE (NBLD * 256)                            // 131072
#define EPT ((2 * N_EDGES + BSTRIDE - 1) / BSTRIDE)     // 13 edges/thread

// float -> bf16 bits, round-to-nearest-even
__device__ __forceinline__ unsigned short f2bf(float f) {
    unsigned u = __float_as_uint(f);
    return (unsigned short)((u + 0x7FFFu + ((u >> 16) & 1u)) >> 16);
}
__device__ __forceinline__ float bf2f(unsigned short b) {
    return __uint_as_float(((unsigned)b) << 16);
}

// Software grid barrier (agent scope). All NBLD blocks are co-resident by
// construction; release (threadfence + release-RMW) / acquire (atomic load)
// give cross-XCD visibility per the HIP memory model (G16 pattern).
__device__ __forceinline__ void grid_barrier(int* bar)
{
    __syncthreads();
    if (threadIdx.x == 0) {
        __threadfence();   // device-scope release of this block's writes
        const int g = __hip_atomic_load(&bar[1], __ATOMIC_RELAXED, __HIP_MEMORY_SCOPE_AGENT);
        const int t = __hip_atomic_fetch_add(&bar[0], 1, __ATOMIC_ACQ_REL, __HIP_MEMORY_SCOPE_AGENT);
        if (t == NBLD - 1) {
            __hip_atomic_store(&bar[0], 0, __ATOMIC_RELAXED, __HIP_MEMORY_SCOPE_AGENT);
            __hip_atomic_fetch_add(&bar[1], 1, __ATOMIC_RELEASE, __HIP_MEMORY_SCOPE_AGENT);
        } else {
            while (__hip_atomic_load(&bar[1], __ATOMIC_RELAXED, __HIP_MEMORY_SCOPE_AGENT) == g)
                __builtin_amdgcn_s_sleep(2);
        }
        // acquire: invalidate stale cached lines before post-barrier reads
        (void)__hip_atomic_load(&bar[1], __ATOMIC_ACQUIRE, __HIP_MEMORY_SCOPE_AGENT);
    }
    __syncthreads();
}

// ---------------------------------------------------------------------------
// Kernel A: per-node precompute (one wave per 4 rows).
//   xm_* stored bf16; s_* and xlin fp32.
// ---------------------------------------------------------------------------
__global__ __launch_bounds__(256) void precompute_kernel(
    const float* __restrict__ x,
    const float* __restrict__ w_l, const float* __restrict__ a_l,
    const float* __restrict__ w_u, const float* __restrict__ a_u,
    const float* __restrict__ w_lin,
    unsigned short* __restrict__ xm_l, unsigned short* __restrict__ xm_u,
    float* __restrict__ s_src_l, float* __restrict__ s_tgt_l,
    float* __restrict__ s_src_u, float* __restrict__ s_tgt_u,
    float* __restrict__ xlin)
{
    __shared__ float lw_l[C * C];
    __shared__ float lw_u[C * C];
    __shared__ float lw_n[C * C];
    __shared__ float la_l[2 * C];
    __shared__ float la_u[2 * C];

    const int t = threadIdx.x;
    for (int idx = t; idx < C * C; idx += 256) {
        lw_l[idx] = w_l[idx];
        lw_u[idx] = w_u[idx];
        lw_n[idx] = w_lin[idx];
    }
    if (t < 2 * C) { la_l[t] = a_l[t]; la_u[t] = a_u[t]; }
    __syncthreads();

    const int wave = t >> 6;
    const int lane = t & 63;
    const int row0 = (blockIdx.x * 4 + wave) * 4;

    float xv[4];
#pragma unroll
    for (int r = 0; r < 4; ++r) {
        const int row = row0 + r;
        xv[r] = (row < N_NODES) ? x[row * C + lane] : 0.f;
    }

    float acc_l[4] = {0.f, 0.f, 0.f, 0.f};
    float acc_u[4] = {0.f, 0.f, 0.f, 0.f};
    float acc_n[4] = {0.f, 0.f, 0.f, 0.f};

#pragma unroll 16
    for (int k = 0; k < C; ++k) {
        const float wl = lw_l[k * C + lane];
        const float wu = lw_u[k * C + lane];
        const float wn = lw_n[k * C + lane];
#pragma unroll
        for (int r = 0; r < 4; ++r) {
            const float xk = __shfl(xv[r], k);
            acc_l[r] = fmaf(xk, wl, acc_l[r]);
            acc_u[r] = fmaf(xk, wu, acc_u[r]);
            acc_n[r] = fmaf(xk, wn, acc_n[r]);
        }
    }

#pragma unroll
    for (int r = 0; r < 4; ++r) {
        const int row = row0 + r;
        if (row >= N_NODES) break;
        xm_l[row * C + lane] = f2bf(acc_l[r]);
        xm_u[row * C + lane] = f2bf(acc_u[r]);
        xlin[row * C + lane] = acc_n[r] * EPS_F;

        float ssl = acc_l[r] * la_l[lane];
        float stl = acc_l[r] * la_l[C + lane];
        float ssu = acc_u[r] * la_u[lane];
        float stu = acc_u[r] * la_u[C + lane];
#pragma unroll
        for (int off = 32; off >= 1; off >>= 1) {
            ssl += __shfl_xor(ssl, off);
            stl += __shfl_xor(stl, off);
            ssu += __shfl_xor(ssu, off);
            stu += __shfl_xor(stu, off);
        }
        if (lane == 0) {
            s_src_l[row] = ssl;
            s_tgt_l[row] = stl;
            s_src_u[row] = ssu;
            s_tgt_u[row] = stu;
        }
    }
}

// ---------------------------------------------------------------------------
// Kernel B (fused CSR build): zero-deg -> hist (edge records held in
// registers) -> tile sums -> scan -> fill. One dispatch instead of four;
// rank array and the second idx/vals pass are eliminated.
// ---------------------------------------------------------------------------
__global__ __launch_bounds__(256, 4) void build_kernel(
    const int* __restrict__ lidx, const float* __restrict__ lval,
    const float* __restrict__ ssl, const float* __restrict__ stl,
    const int* __restrict__ uidx, const float* __restrict__ uval,
    const float* __restrict__ ssu, const float* __restrict__ stu,
    int* __restrict__ deg, int* __restrict__ bsum, int* __restrict__ off,
    float2* __restrict__ rec, int* bar)
{
    const int b = blockIdx.x, t = threadIdx.x;
    const int tid = b * 256 + t;
    const int lane = t & 63, wv = t >> 6;
    const int p = b & (NPART - 1);

    __shared__ int wsum[4];
    __shared__ int pre4[4];

    // ---- Phase 0: zero the degree histogram ----
    for (int k = tid; k < DEG_PAD; k += BSTRIDE) deg[k] = 0;
    grid_barrier(bar);

    // ---- Phase 1: histogram + per-edge records in registers ----
    int jj[EPT]; float aa[EPT]; int bb[EPT]; int rr[EPT];
#pragma unroll
    for (int k = 0; k < EPT; ++k) {
        const int g = tid + k * BSTRIDE;
        bb[k] = -1; jj[k] = 0; rr[k] = 0; aa[k] = 0.f;
        if (g < 2 * N_EDGES) {
            int i, j; float v, s;
            if (g < N_EDGES) {
                i = lidx[g]; j = lidx[N_EDGES + g]; v = lval[g];
                s = ssl[j] + stl[i];
                bb[k] = p * TWO_N + i;
            } else {
                const int e = g - N_EDGES;
                i = uidx[e]; j = uidx[N_EDGES + e]; v = uval[e];
                s = ssu[j] + stu[i];
                bb[k] = p * TWO_N + N_NODES + i;
            }
            s = (s > 0.f) ? s : expm1f(s);
            aa[k] = s * v;
            jj[k] = j;
            rr[k] = atomicAdd(&deg[bb[k]], 1);
        }
    }
    grid_barrier(bar);

    // ---- Phase 2: per-tile sums (blocks 0..NB_SCAN-1) ----
    if (b < NB_SCAN) {
        const int4 d = ((const int4*)deg)[b * 256 + t];
        int v = d.x + d.y + d.z + d.w;
#pragma unroll
        for (int o = 32; o >= 1; o >>= 1) v += __shfl_xor(v, o);
        if (lane == 0) wsum[wv] = v;
        __syncthreads();
        if (t == 0) bsum[b] = wsum[0] + wsum[1] + wsum[2] + wsum[3];
    }
    grid_barrier(bar);

    // ---- Phase 3: exclusive scan of deg into off[] ----
    if (b < NB_SCAN) {
        int part = 0;
        for (int i = t; i < NB_SCAN; i += 256)
            part += (i < b) ? bsum[i] : 0;
#pragma unroll
        for (int o = 32; o >= 1; o >>= 1) part += __shfl_xor(part, o);
        if (lane == 0) pre4[wv] = part;
        __syncthreads();
        const int bpre = pre4[0] + pre4[1] + pre4[2] + pre4[3];

        const int g4 = (b * 256 + t) * 4;
        const int4 d = ((const int4*)deg)[b * 256 + t];
        const int e1 = d.x, e2 = d.x + d.y, e3 = d.x + d.y + d.z;
        const int tot = e3 + d.w;

        int inc = tot;
#pragma unroll
        for (int o = 1; o < 64; o <<= 1) {
            const int y = __shfl_up(inc, o);
            if (lane >= o) inc += y;
        }
        __syncthreads();                 // reuse wsum safely
        if (lane == 63) wsum[wv] = inc;
        __syncthreads();
        int wpre = 0;
        for (int w = 0; w < wv; ++w) wpre += wsum[w];

        const int base = bpre + wpre + (inc - tot);
        const int vals[4] = { base, base + e1, base + e2, base + e3 };
#pragma unroll
        for (int k = 0; k < 4; ++k) {
            const int f = g4 + k;
            if (f <= DEG_SZ) off[f] = vals[k];
        }
    }
    grid_barrier(bar);

    // ---- Phase 4: fill rec[] from registers ----
#pragma unroll
    for (int k = 0; k < EPT; ++k) {
        if (bb[k] >= 0) {
            rec[off[bb[k]] + rr[k]] = make_float2(__int_as_float(jj[k]), aa[k]);
        }
    }
}

// ---------------------------------------------------------------------------
// Kernel D: gather + fuse. One BLOCK per node. Wave w: conv = w>>1,
// partitions (w&1)*2..+1. sub = lane>>4 picks 1 of 4 sequential records per
// chunk, cg = lane&15 picks 4 channels (ushort4 load) -> one wave-wide load
// serves 4 records. shfl_xor + LDS reduce, + xlin, ReLU, float4 store.
// ---------------------------------------------------------------------------
__global__ __launch_bounds__(256) void gather_kernel(
    const float* __restrict__ xlin,
    const int* __restrict__ off, const float2* __restrict__ rec,
    const unsigned short* __restrict__ xm_l, const unsigned short* __restrict__ xm_u,
    float* __restrict__ out)
{
    const int node = blockIdx.x;
    const int wv = threadIdx.x >> 6;
    const int lane = threadIdx.x & 63;
    const int conv = wv >> 1;
    const int pbase = (wv & 1) * 2;
    const unsigned short* __restrict__ xm = conv ? xm_u : xm_l;
    const int sub = lane >> 4;
    const int cg = lane & 15;

    float4 acc = make_float4(0.f, 0.f, 0.f, 0.f);

#pragma unroll
    for (int sseg = 0; sseg < 2; ++sseg) {
        const int f = (pbase + sseg) * TWO_N + conv * N_NODES + node;
        int k = off[f];
        const int e = off[f + 1];
        while (k < e) {
            const int idx = k + sub;
            const bool act = idx < e;
            const float2 r = rec[act ? idx : k];
            const int j = act ? __float_as_int(r.x) : 0;
            const float w = act ? r.y : 0.f;
            const ushort4 row = *(const ushort4*)(xm + j * C + cg * 4);
            acc.x = fmaf(w, bf2f(row.x), acc.x);
            acc.y = fmaf(w, bf2f(row.y), acc.y);
            acc.z = fmaf(w, bf2f(row.z), acc.z);
            acc.w = fmaf(w, bf2f(row.w), acc.w);
            k += 4;
        }
    }

    acc.x += __shfl_xor(acc.x, 16);
    acc.y += __shfl_xor(acc.y, 16);
    acc.z += __shfl_xor(acc.z, 16);
    acc.w += __shfl_xor(acc.w, 16);
    acc.x += __shfl_xor(acc.x, 32);
    acc.y += __shfl_xor(acc.y, 32);
    acc.z += __shfl_xor(acc.z, 32);
    acc.w += __shfl_xor(acc.w, 32);

    __shared__ float4 red[4][16];
    if (lane < 16) red[wv][lane] = acc;
    __syncthreads();
    if (wv == 0 && lane < 16) {
        const float4 a0 = red[0][lane];
        const float4 a1 = red[1][lane];
        const float4 a2 = red[2][lane];
        const float4 a3 = red[3][lane];
        const float4 xl = *(const float4*)(xlin + node * C + lane * 4);
        float4 o;
        o.x = fmaxf(xl.x + a0.x + a1.x + a2.x + a3.x, 0.f);
        o.y = fmaxf(xl.y + a0.y + a1.y + a2.y + a3.y, 0.f);
        o.z = fmaxf(xl.z + a0.z + a1.z + a2.z + a3.z, 0.f);
        o.w = fmaxf(xl.w + a0.w + a1.w + a2.w + a3.w, 0.f);
        *(float4*)(out + node * C + lane * 4) = o;
    }
}

extern "C" void kernel_launch(void* const* d_in, const int* in_sizes, int n_in,
                              void* d_out, int out_size, void* d_ws, size_t ws_size,
                              hipStream_t stream)
{
    const float* x          = (const float*)d_in[0];
    const int*   lower_idx  = (const int*)d_in[1];
    const float* lower_vals = (const float*)d_in[2];
    const int*   upper_idx  = (const int*)d_in[3];
    const float* upper_vals = (const float*)d_in[4];
    const float* w_lower    = (const float*)d_in[5];
    const float* a_lower    = (const float*)d_in[6];
    const float* w_upper    = (const float*)d_in[7];
    const float* a_upper    = (const float*)d_in[8];
    const float* w_lin      = (const float*)d_in[9];

    float* out = (float*)d_out;
    char* ws = (char*)d_ws;

    // ---- workspace layout ----
    const size_t NC_F = (size_t)N_NODES * C * sizeof(float);          // 12.8 MB
    const size_t NC_H = (size_t)N_NODES * C * sizeof(unsigned short); // 6.4 MB
    unsigned short* xm_l = (unsigned short*)ws;  ws += NC_H;
    unsigned short* xm_u = (unsigned short*)ws;  ws += NC_H;
    float* xlin = (float*)ws;                 ws += NC_F;
    float* ssl  = (float*)ws;                 ws += N_NODES * sizeof(float);
    float* stl  = (float*)ws;                 ws += N_NODES * sizeof(float);
    float* ssu  = (float*)ws;                 ws += N_NODES * sizeof(float);
    float* stu  = (float*)ws;                 ws += N_NODES * sizeof(float);
    int* deg    = (int*)ws;                   ws += DEG_PAD * sizeof(int);
    int* off    = (int*)ws;                   ws += (DEG_SZ + 16) * sizeof(int);
    int* bsum   = (int*)ws;                   ws += ((NB_SCAN + 15) & ~15) * sizeof(int);
    int* bar    = (int*)ws;                   ws += 16 * sizeof(int);   // {cnt, gen}
    float2* rec = (float2*)ws;                ws += (size_t)(2 * N_EDGES) * sizeof(float2);

    // barrier state must start zeroed every launch (ws is re-poisoned)
    hipMemsetAsync(bar, 0, 16 * sizeof(int), stream);

    // A: per-node precompute
    precompute_kernel<<<(N_NODES + 15) / 16, 256, 0, stream>>>(
        x, w_lower, a_lower, w_upper, a_upper, w_lin,
        xm_l, xm_u, ssl, stl, ssu, stu, xlin);

    // B: fused CSR build (hist + scan + fill in one dispatch)
    build_kernel<<<NBLD, 256, 0, stream>>>(
        lower_idx, lower_vals, ssl, stl,
        upper_idx, upper_vals, ssu, stu,
        deg, bsum, off, rec, bar);

    // D: gather + skip + relu
    gather_kernel<<<N_NODES, 256, 0, stream>>>(
        xlin, off, rec, xm_l, xm_u, out);
}

// Round 8
// 339.488 us; speedup vs baseline: 1.6237x; 1.6237x over previous
//
#include <hip/hip_runtime.h>
#include <hip/hip_bf16.h>
#include <math.h>

#define N_NODES 50000
#define N_EDGES 800000
#define C 64
#define EPS_F 1.000001f
#define TWO_N (2 * N_NODES)

// CSR partitioned by edge-chunk cohort p = chunk & 3 (matches round-robin XCD
// dispatch of the fill grid) -> rec[] cache-line writers stay on a fixed XCD
// cohort (fixes the 8x HBM write amp seen in round 3), while keeping gather
// segments at avg len 4 = one 4-record chunk (round-5/6 lesson).
#define NPART 4
#define DEG_SZ (NPART * TWO_N)                          // 400000 bins
#define SCAN_TILE 1024
#define NB_SCAN ((DEG_SZ + SCAN_TILE - 1) / SCAN_TILE)  // 391 tiles
#define DEG_PAD (NB_SCAN * SCAN_TILE)                   // 400384

#define NPRE 1563                 // ceil(50000/32) precompute blocks (32 rows each)
#define NHIST ((2 * N_EDGES + 255) / 256)               // 6250
#define NK1 (NPRE * 5)            // interleave 4 hist : 1 pre -> 7815 blocks
#define NSB 6250                  // s-compute blocks (8 rows each)

// float -> bf16 bits, round-to-nearest-even
__device__ __forceinline__ unsigned short f2bf(float f) {
    unsigned u = __float_as_uint(f);
    return (unsigned short)((u + 0x7FFFu + ((u >> 16) & 1u)) >> 16);
}
__device__ __forceinline__ float bf2f(unsigned short b) {
    return __uint_as_float(((unsigned)b) << 16);
}

// ---------------------------------------------------------------------------
// Kernel 1 (fused): precompute (blocks with b%5==4) + degree histogram
// (b%5!=4). Both roles are fully parallel (no grid barrier — round-7 lesson).
//
// Precompute: 8 rows per wave. Row index is wave-uniform (readfirstlane), so
// x[row][k] loads are scalar (SMEM) — no shfl/bpermute. Weights staged fp32
// in LDS; per k-iter: 3 ds_read_b32 + 24 v_fmac (SGPR x-operand). The s_*
// attention scalars are NOT computed here (moved to kernel 2b) so the
// epilogue is pure stores.
// ---------------------------------------------------------------------------
__global__ __launch_bounds__(256) void pre_hist_kernel(
    const float* __restrict__ x,
    const float* __restrict__ w_l, const float* __restrict__ w_u,
    const float* __restrict__ w_lin,
    const int* __restrict__ lidx, const int* __restrict__ uidx,
    unsigned short* __restrict__ xm_l, unsigned short* __restrict__ xm_u,
    float* __restrict__ xlin, int* __restrict__ deg)
{
    const int b = blockIdx.x;
    const int t = threadIdx.x;
    const int r5 = b % 5;

    if (r5 != 4) {
        // ---- hist role: edge-chunk h, partition p = h & 3 ----
        const int h = (b / 5) * 4 + r5;
        const int g = h * 256 + t;
        if (g < 2 * N_EDGES) {
            const int p = h & (NPART - 1);
            int bin;
            if (g < N_EDGES) bin = p * TWO_N + lidx[g];
            else             bin = p * TWO_N + N_NODES + uidx[g - N_EDGES];
            atomicAdd(&deg[bin], 1);   // no return use -> fire-and-forget
        }
        return;
    }

    // ---- precompute role ----
    __shared__ float lw[3 * C * C];    // [w_l | w_u | w_lin], 48 KB
    for (int idx = t; idx < C * C; idx += 256) {
        lw[idx]             = w_l[idx];
        lw[C * C + idx]     = w_u[idx];
        lw[2 * C * C + idx] = w_lin[idx];
    }
    __syncthreads();

    const int pb = b / 5;
    const int lane = t & 63;
    const int wvu = __builtin_amdgcn_readfirstlane(t >> 6);
    const int row0 = pb * 32 + wvu * 8;
    if (row0 >= N_NODES) return;

    // wave-uniform row pointers (clamped; stores are guarded)
    const float* xr[8];
#pragma unroll
    for (int r = 0; r < 8; ++r) {
        int rr = row0 + r;
        if (rr >= N_NODES) rr = N_NODES - 1;
        xr[r] = x + (size_t)rr * C;
    }

    float acc_l[8] = {0,0,0,0,0,0,0,0};
    float acc_u[8] = {0,0,0,0,0,0,0,0};
    float acc_n[8] = {0,0,0,0,0,0,0,0};

#pragma unroll 1
    for (int kc = 0; kc < C; kc += 4) {
#pragma unroll
        for (int kk = 0; kk < 4; ++kk) {
            const int k = kc + kk;
            const float wl = lw[k * C + lane];
            const float wu = lw[C * C + k * C + lane];
            const float wn = lw[2 * C * C + k * C + lane];
#pragma unroll
            for (int r = 0; r < 8; ++r) {
                const float xk = xr[r][k];     // uniform -> scalar load
                acc_l[r] = fmaf(xk, wl, acc_l[r]);
                acc_u[r] = fmaf(xk, wu, acc_u[r]);
                acc_n[r] = fmaf(xk, wn, acc_n[r]);
            }
        }
    }

#pragma unroll
    for (int r = 0; r < 8; ++r) {
        const int row = row0 + r;
        if (row < N_NODES) {
            xm_l[row * C + lane] = f2bf(acc_l[r]);
            xm_u[row * C + lane] = f2bf(acc_u[r]);
            xlin[row * C + lane] = acc_n[r] * EPS_F;
        }
    }
}

// ---------------------------------------------------------------------------
// Kernel 2 (fused): blocks [0, NB_SCAN) do per-tile deg sums; blocks
// [NB_SCAN, NB_SCAN+NSB) compute the attention scalars from bf16 xm:
//   s_src[row] = xm[row] . a[0:64] ; s_tgt[row] = xm[row] . a[64:128]
// 8 rows/block: wave w -> conv w>>1, rows (w&1)*4 + (lane>>4); 16 lanes/row.
// ---------------------------------------------------------------------------
__global__ __launch_bounds__(256) void bsum_s_kernel(
    const int* __restrict__ deg, int* __restrict__ bsum,
    const unsigned short* __restrict__ xm_l, const unsigned short* __restrict__ xm_u,
    const float* __restrict__ a_l, const float* __restrict__ a_u,
    float* __restrict__ ssl, float* __restrict__ stl,
    float* __restrict__ ssu, float* __restrict__ stu)
{
    const int b = blockIdx.x;
    const int t = threadIdx.x;
    const int lane = t & 63, wv = t >> 6;

    if (b < NB_SCAN) {
        const int4 d = ((const int4*)deg)[b * 256 + t];
        int v = d.x + d.y + d.z + d.w;
#pragma unroll
        for (int o = 32; o >= 1; o >>= 1) v += __shfl_xor(v, o);
        __shared__ int ws4[4];
        if (lane == 0) ws4[wv] = v;
        __syncthreads();
        if (t == 0) bsum[b] = ws4[0] + ws4[1] + ws4[2] + ws4[3];
        return;
    }

    const int sb = b - NB_SCAN;
    const int conv = wv >> 1;
    const int row = sb * 8 + (wv & 1) * 4 + (lane >> 4);
    const int c4 = lane & 15;
    if (row >= N_NODES) return;

    const unsigned short* __restrict__ xm = conv ? xm_u : xm_l;
    const float* __restrict__ av = conv ? a_u : a_l;

    const ushort4 m = *(const ushort4*)(xm + row * C + c4 * 4);
    const float m0 = bf2f(m.x), m1 = bf2f(m.y), m2 = bf2f(m.z), m3 = bf2f(m.w);

    float ps = m0 * av[c4 * 4] + m1 * av[c4 * 4 + 1]
             + m2 * av[c4 * 4 + 2] + m3 * av[c4 * 4 + 3];
    float pt = m0 * av[C + c4 * 4] + m1 * av[C + c4 * 4 + 1]
             + m2 * av[C + c4 * 4 + 2] + m3 * av[C + c4 * 4 + 3];
#pragma unroll
    for (int o = 1; o <= 8; o <<= 1) {
        ps += __shfl_xor(ps, o);
        pt += __shfl_xor(pt, o);
    }
    if (c4 == 0) {
        if (conv) { ssu[row] = ps; stu[row] = pt; }
        else      { ssl[row] = ps; stl[row] = pt; }
    }
}

// ---------------------------------------------------------------------------
// Kernel 3: exclusive scan of deg into off[] AND cur[] (cur is fill's atomic
// cursor). Each block redundantly prefix-sums the 391 tile sums (cheap).
// ---------------------------------------------------------------------------
__global__ __launch_bounds__(256) void scan_apply_kernel(
    const int* __restrict__ deg, const int* __restrict__ bsum,
    int* __restrict__ off, int* __restrict__ cur)
{
    const int b = blockIdx.x, t = threadIdx.x;
    const int lane = t & 63, wv = t >> 6;

    int part = 0;
    for (int i = t; i < NB_SCAN; i += 256)
        part += (i < b) ? bsum[i] : 0;
#pragma unroll
    for (int o = 32; o >= 1; o >>= 1) part += __shfl_xor(part, o);
    __shared__ int pre4[4];
    if (lane == 0) pre4[wv] = part;
    __syncthreads();
    const int bpre = pre4[0] + pre4[1] + pre4[2] + pre4[3];

    const int g4 = (b * 256 + t) * 4;
    const int4 d = ((const int4*)deg)[b * 256 + t];
    const int e1 = d.x, e2 = d.x + d.y, e3 = d.x + d.y + d.z;
    const int tot = e3 + d.w;

    int inc = tot;
#pragma unroll
    for (int o = 1; o < 64; o <<= 1) {
        const int y = __shfl_up(inc, o);
        if (lane >= o) inc += y;
    }
    __shared__ int wsum[4];
    if (lane == 63) wsum[wv] = inc;
    __syncthreads();
    int wpre = 0;
    for (int w = 0; w < wv; ++w) wpre += wsum[w];

    const int base = bpre + wpre + (inc - tot);
    const int vals[4] = { base, base + e1, base + e2, base + e3 };
#pragma unroll
    for (int k = 0; k < 4; ++k) {
        const int f = g4 + k;
        if (f < DEG_SZ) { off[f] = vals[k]; cur[f] = vals[k]; }
        else if (f == DEG_SZ) off[f] = vals[k];
    }
}

// ---------------------------------------------------------------------------
// Kernel 4: CSR fill. Per edge: alpha = elu(s_src[j]+s_tgt[i])*val; claim a
// slot under (p, conv, target) via atomic cursor. p = blockIdx & 3 (== edge
// chunk & 3, matching hist's p).
// ---------------------------------------------------------------------------
__global__ __launch_bounds__(256) void fill_kernel(
    const int* __restrict__ lidx, const float* __restrict__ lval,
    const float* __restrict__ ssl, const float* __restrict__ stl,
    const int* __restrict__ uidx, const float* __restrict__ uval,
    const float* __restrict__ ssu, const float* __restrict__ stu,
    int* __restrict__ cur, float2* __restrict__ rec)
{
    const int g = blockIdx.x * 256 + threadIdx.x;
    const int p = blockIdx.x & (NPART - 1);
    if (g >= 2 * N_EDGES) return;

    int bin, j;
    float s, v;
    if (g < N_EDGES) {
        const int i = lidx[g];
        j = lidx[N_EDGES + g];
        v = lval[g];
        s = ssl[j] + stl[i];
        bin = p * TWO_N + i;
    } else {
        const int e = g - N_EDGES;
        const int i = uidx[e];
        j = uidx[N_EDGES + e];
        v = uval[e];
        s = ssu[j] + stu[i];
        bin = p * TWO_N + N_NODES + i;
    }
    s = (s > 0.f) ? s : expm1f(s);
    const float a = s * v;
    const int slot = atomicAdd(&cur[bin], 1);
    rec[slot] = make_float2(__int_as_float(j), a);
}

// ---------------------------------------------------------------------------
// Kernel 5: gather + fuse (unchanged from round 6: 97 us, random-line-bound).
// One BLOCK per node. Wave w: conv = w>>1, partitions (w&1)*2..+1.
// sub = lane>>4 picks 1 of 4 sequential records per chunk, cg = lane&15 picks
// 4 channels (ushort4) -> one wave-wide load serves 4 records.
// ---------------------------------------------------------------------------
__global__ __launch_bounds__(256) void gather_kernel(
    const float* __restrict__ xlin,
    const int* __restrict__ off, const float2* __restrict__ rec,
    const unsigned short* __restrict__ xm_l, const unsigned short* __restrict__ xm_u,
    float* __restrict__ out)
{
    const int node = blockIdx.x;
    const int wv = threadIdx.x >> 6;
    const int lane = threadIdx.x & 63;
    const int conv = wv >> 1;
    const int pbase = (wv & 1) * 2;
    const unsigned short* __restrict__ xm = conv ? xm_u : xm_l;
    const int sub = lane >> 4;
    const int cg = lane & 15;

    float4 acc = make_float4(0.f, 0.f, 0.f, 0.f);

#pragma unroll
    for (int sseg = 0; sseg < 2; ++sseg) {
        const int f = (pbase + sseg) * TWO_N + conv * N_NODES + node;
        int k = off[f];
        const int e = off[f + 1];
        while (k < e) {
            const int idx = k + sub;
            const bool act = idx < e;
            const float2 r = rec[act ? idx : k];
            const int j = act ? __float_as_int(r.x) : 0;
            const float w = act ? r.y : 0.f;
            const ushort4 row = *(const ushort4*)(xm + j * C + cg * 4);
            acc.x = fmaf(w, bf2f(row.x), acc.x);
            acc.y = fmaf(w, bf2f(row.y), acc.y);
            acc.z = fmaf(w, bf2f(row.z), acc.z);
            acc.w = fmaf(w, bf2f(row.w), acc.w);
            k += 4;
        }
    }

    acc.x += __shfl_xor(acc.x, 16);
    acc.y += __shfl_xor(acc.y, 16);
    acc.z += __shfl_xor(acc.z, 16);
    acc.w += __shfl_xor(acc.w, 16);
    acc.x += __shfl_xor(acc.x, 32);
    acc.y += __shfl_xor(acc.y, 32);
    acc.z += __shfl_xor(acc.z, 32);
    acc.w += __shfl_xor(acc.w, 32);

    __shared__ float4 red[4][16];
    if (lane < 16) red[wv][lane] = acc;
    __syncthreads();
    if (wv == 0 && lane < 16) {
        const float4 a0 = red[0][lane];
        const float4 a1 = red[1][lane];
        const float4 a2 = red[2][lane];
        const float4 a3 = red[3][lane];
        const float4 xl = *(const float4*)(xlin + node * C + lane * 4);
        float4 o;
        o.x = fmaxf(xl.x + a0.x + a1.x + a2.x + a3.x, 0.f);
        o.y = fmaxf(xl.y + a0.y + a1.y + a2.y + a3.y, 0.f);
        o.z = fmaxf(xl.z + a0.z + a1.z + a2.z + a3.z, 0.f);
        o.w = fmaxf(xl.w + a0.w + a1.w + a2.w + a3.w, 0.f);
        *(float4*)(out + node * C + lane * 4) = o;
    }
}

extern "C" void kernel_launch(void* const* d_in, const int* in_sizes, int n_in,
                              void* d_out, int out_size, void* d_ws, size_t ws_size,
                              hipStream_t stream)
{
    const float* x          = (const float*)d_in[0];
    const int*   lower_idx  = (const int*)d_in[1];
    const float* lower_vals = (const float*)d_in[2];
    const int*   upper_idx  = (const int*)d_in[3];
    const float* upper_vals = (const float*)d_in[4];
    const float* w_lower    = (const float*)d_in[5];
    const float* a_lower    = (const float*)d_in[6];
    const float* w_upper    = (const float*)d_in[7];
    const float* a_upper    = (const float*)d_in[8];
    const float* w_lin      = (const float*)d_in[9];

    float* out = (float*)d_out;
    char* ws = (char*)d_ws;

    // ---- workspace layout ----
    const size_t NC_F = (size_t)N_NODES * C * sizeof(float);          // 12.8 MB
    const size_t NC_H = (size_t)N_NODES * C * sizeof(unsigned short); // 6.4 MB
    unsigned short* xm_l = (unsigned short*)ws;  ws += NC_H;
    unsigned short* xm_u = (unsigned short*)ws;  ws += NC_H;
    float* xlin = (float*)ws;                 ws += NC_F;
    float* ssl  = (float*)ws;                 ws += N_NODES * sizeof(float);
    float* stl  = (float*)ws;                 ws += N_NODES * sizeof(float);
    float* ssu  = (float*)ws;                 ws += N_NODES * sizeof(float);
    float* stu  = (float*)ws;                 ws += N_NODES * sizeof(float);
    int* deg    = (int*)ws;                   ws += DEG_PAD * sizeof(int);
    int* off    = (int*)ws;                   ws += (DEG_SZ + 16) * sizeof(int);
    int* cur    = (int*)ws;                   ws += (DEG_SZ + 16) * sizeof(int);
    int* bsum   = (int*)ws;                   ws += ((NB_SCAN + 15) & ~15) * sizeof(int);
    float2* rec = (float2*)ws;                ws += (size_t)(2 * N_EDGES) * sizeof(float2);

    // deg must be zero before hist atomics (K1)
    hipMemsetAsync(deg, 0, DEG_PAD * sizeof(int), stream);

    // K1: fused precompute + histogram
    pre_hist_kernel<<<NK1, 256, 0, stream>>>(
        x, w_lower, w_upper, w_lin, lower_idx, upper_idx,
        xm_l, xm_u, xlin, deg);

    // K2: fused tile sums + attention scalars
    bsum_s_kernel<<<NB_SCAN + NSB, 256, 0, stream>>>(
        deg, bsum, xm_l, xm_u, a_lower, a_upper, ssl, stl, ssu, stu);

    // K3: scan -> off + cur
    scan_apply_kernel<<<NB_SCAN, 256, 0, stream>>>(deg, bsum, off, cur);

    // K4: CSR fill (atomic cursor)
    fill_kernel<<<(2 * N_EDGES + 255) / 256, 256, 0, stream>>>(
        lower_idx, lower_vals, ssl, stl,
        upper_idx, upper_vals, ssu, stu,
        cur, rec);

    // K5: gather + skip + relu
    gather_kernel<<<N_NODES, 256, 0, stream>>>(
        xlin, off, rec, xm_l, xm_u, out);
}

// Round 9
// 298.469 us; speedup vs baseline: 1.8468x; 1.1374x over previous
//
#include <hip/hip_runtime.h>
#include <hip/hip_bf16.h>
#include <math.h>

#define N_NODES 50000
#define N_EDGES 800000
#define C 64
#define EPS_F 1.000001f
#define TWO_N (2 * N_NODES)

// CSR-free direct buckets: bin = [p][conv][node], each with a fixed CAP-slot
// slab. p = edge-chunk & 3 keeps each cohort's cnt/rec writes on a fixed XCD
// pair (round-3 lesson: unpartitioned scatter = 8x HBM write amp). CAP=24:
// bin degree ~ Poisson(4); P(any bin > 24) ~ 4e-6 -> effectively never drops.
#define NPART 4
#define DEG_SZ (NPART * TWO_N)     // 400000 bins
#define CAP 24                     // slots/bin; rec32 = 400K*24*4B = 38.4 MB

#define NPRE ((N_NODES + 31) / 32)              // 1563 blocks (32 rows each)
#define NEDGE_B ((2 * N_EDGES + 255) / 256)     // 6250 edge blocks

// float <-> bf16 bits (round-to-nearest-even)
__device__ __forceinline__ unsigned short f2bf(float f) {
    unsigned u = __float_as_uint(f);
    return (unsigned short)((u + 0x7FFFu + ((u >> 16) & 1u)) >> 16);
}
__device__ __forceinline__ float bf2f(unsigned short b) {
    return __uint_as_float(((unsigned)b) << 16);
}

// ---------------------------------------------------------------------------
// Kernel 1: precompute + attention scalars + zero cnt[].  8 rows per wave;
// row index wave-uniform (readfirstlane) so x[row][k] loads go through the
// scalar unit; weights staged fp32 in LDS. s_* reduced from the fp32
// accumulators already in registers (no extra xm pass).
// ---------------------------------------------------------------------------
__global__ __launch_bounds__(256) void pre_kernel(
    const float* __restrict__ x,
    const float* __restrict__ w_l, const float* __restrict__ a_l,
    const float* __restrict__ w_u, const float* __restrict__ a_u,
    const float* __restrict__ w_lin,
    unsigned short* __restrict__ xm_l, unsigned short* __restrict__ xm_u,
    float* __restrict__ xlin,
    float* __restrict__ ssl, float* __restrict__ stl,
    float* __restrict__ ssu, float* __restrict__ stu,
    int* __restrict__ cnt)
{
    const int b = blockIdx.x;
    const int t = threadIdx.x;

    // fused cnt zeroing: 1563*256 = 400128 threads >= DEG_SZ
    const int gz = b * 256 + t;
    if (gz < DEG_SZ) cnt[gz] = 0;

    __shared__ float lw[3 * C * C];    // [w_l | w_u | w_lin], 48 KB
    for (int idx = t; idx < C * C; idx += 256) {
        lw[idx]             = w_l[idx];
        lw[C * C + idx]     = w_u[idx];
        lw[2 * C * C + idx] = w_lin[idx];
    }
    __syncthreads();

    const int lane = t & 63;
    const int wvu = __builtin_amdgcn_readfirstlane(t >> 6);
    const int row0 = b * 32 + wvu * 8;
    if (row0 >= N_NODES) return;

    // attention vectors, one element per lane (register resident)
    const float al_s = a_l[lane], al_t = a_l[C + lane];
    const float au_s = a_u[lane], au_t = a_u[C + lane];

    // wave-uniform row pointers (clamped; stores guarded)
    const float* xr[8];
#pragma unroll
    for (int r = 0; r < 8; ++r) {
        int rr = row0 + r;
        if (rr >= N_NODES) rr = N_NODES - 1;
        xr[r] = x + (size_t)rr * C;
    }

    float acc_l[8] = {0,0,0,0,0,0,0,0};
    float acc_u[8] = {0,0,0,0,0,0,0,0};
    float acc_n[8] = {0,0,0,0,0,0,0,0};

#pragma unroll 1
    for (int kc = 0; kc < C; kc += 4) {
#pragma unroll
        for (int kk = 0; kk < 4; ++kk) {
            const int k = kc + kk;
            const float wl = lw[k * C + lane];
            const float wu = lw[C * C + k * C + lane];
            const float wn = lw[2 * C * C + k * C + lane];
#pragma unroll
            for (int r = 0; r < 8; ++r) {
                const float xk = xr[r][k];     // uniform -> scalar load
                acc_l[r] = fmaf(xk, wl, acc_l[r]);
                acc_u[r] = fmaf(xk, wu, acc_u[r]);
                acc_n[r] = fmaf(xk, wn, acc_n[r]);
            }
        }
    }

#pragma unroll
    for (int r = 0; r < 8; ++r) {
        const int row = row0 + r;
        if (row >= N_NODES) break;
        xm_l[row * C + lane] = f2bf(acc_l[r]);
        xm_u[row * C + lane] = f2bf(acc_u[r]);
        xlin[row * C + lane] = acc_n[r] * EPS_F;

        float psl = acc_l[r] * al_s;
        float ptl = acc_l[r] * al_t;
        float psu = acc_u[r] * au_s;
        float ptu = acc_u[r] * au_t;
#pragma unroll
        for (int o = 32; o >= 1; o >>= 1) {
            psl += __shfl_xor(psl, o);
            ptl += __shfl_xor(ptl, o);
            psu += __shfl_xor(psu, o);
            ptu += __shfl_xor(ptu, o);
        }
        if (lane == 0) {
            ssl[row] = psl;
            stl[row] = ptl;
            ssu[row] = psu;
            stu[row] = ptu;
        }
    }
}

// ---------------------------------------------------------------------------
// Kernel 2: direct-bucket fill. Per edge: alpha = elu(s_src[j]+s_tgt[i])*val;
// rank = atomicAdd(cnt[bin]); rec32[bin*CAP+rank] = {j:16 | bf16(alpha):16}.
// No histogram pass, no scan — the slab base is bin*CAP.
// ---------------------------------------------------------------------------
__global__ __launch_bounds__(256) void fill_kernel(
    const int* __restrict__ lidx, const float* __restrict__ lval,
    const float* __restrict__ ssl, const float* __restrict__ stl,
    const int* __restrict__ uidx, const float* __restrict__ uval,
    const float* __restrict__ ssu, const float* __restrict__ stu,
    int* __restrict__ cnt, unsigned* __restrict__ rec)
{
    const int g = blockIdx.x * 256 + threadIdx.x;
    const int p = blockIdx.x & (NPART - 1);
    if (g >= 2 * N_EDGES) return;

    int bin, j;
    float s, v;
    if (g < N_EDGES) {
        const int i = lidx[g];
        j = lidx[N_EDGES + g];
        v = lval[g];
        s = ssl[j] + stl[i];
        bin = p * TWO_N + i;
    } else {
        const int e = g - N_EDGES;
        const int i = uidx[e];
        j = uidx[N_EDGES + e];
        v = uval[e];
        s = ssu[j] + stu[i];
        bin = p * TWO_N + N_NODES + i;
    }
    s = (s > 0.f) ? s : expm1f(s);
    const float a = s * v;
    const int rank = atomicAdd(&cnt[bin], 1);
    if (rank < CAP)
        rec[(size_t)bin * CAP + rank] = ((unsigned)j << 16) | (unsigned)f2bf(a);
}

// ---------------------------------------------------------------------------
// Kernel 3: gather + fuse. One BLOCK per node. Wave w: conv = w>>1,
// partitions (w&1)*2..+1. sub = lane>>4 picks 1 of 4 sequential records per
// chunk, cg = lane&15 picks 4 channels (ushort4) -> one wave-wide load serves
// 4 records. Segment base/len come from bin*CAP and cnt[bin] (no off[]).
// ---------------------------------------------------------------------------
__global__ __launch_bounds__(256) void gather_kernel(
    const float* __restrict__ xlin,
    const int* __restrict__ cnt, const unsigned* __restrict__ rec,
    const unsigned short* __restrict__ xm_l, const unsigned short* __restrict__ xm_u,
    float* __restrict__ out)
{
    const int node = blockIdx.x;
    const int wv = threadIdx.x >> 6;
    const int lane = threadIdx.x & 63;
    const int conv = wv >> 1;
    const int pbase = (wv & 1) * 2;
    const unsigned short* __restrict__ xm = conv ? xm_u : xm_l;
    const int sub = lane >> 4;
    const int cg = lane & 15;

    float4 acc = make_float4(0.f, 0.f, 0.f, 0.f);

#pragma unroll
    for (int sseg = 0; sseg < 2; ++sseg) {
        const int bin = (pbase + sseg) * TWO_N + conv * N_NODES + node;
        const int len = min(cnt[bin], CAP);
        const unsigned* __restrict__ rb = rec + (size_t)bin * CAP;
        int k = 0;
        while (k < len) {
            const int idx = k + sub;
            const bool act = idx < len;
            const unsigned rw = rb[act ? idx : 0];   // slot 0 valid when len>0
            const int j = (int)(rw >> 16);
            const float w = act ? bf2f((unsigned short)(rw & 0xFFFFu)) : 0.f;
            const ushort4 row = *(const ushort4*)(xm + j * C + cg * 4);
            acc.x = fmaf(w, bf2f(row.x), acc.x);
            acc.y = fmaf(w, bf2f(row.y), acc.y);
            acc.z = fmaf(w, bf2f(row.z), acc.z);
            acc.w = fmaf(w, bf2f(row.w), acc.w);
            k += 4;
        }
    }

    acc.x += __shfl_xor(acc.x, 16);
    acc.y += __shfl_xor(acc.y, 16);
    acc.z += __shfl_xor(acc.z, 16);
    acc.w += __shfl_xor(acc.w, 16);
    acc.x += __shfl_xor(acc.x, 32);
    acc.y += __shfl_xor(acc.y, 32);
    acc.z += __shfl_xor(acc.z, 32);
    acc.w += __shfl_xor(acc.w, 32);

    __shared__ float4 red[4][16];
    if (lane < 16) red[wv][lane] = acc;
    __syncthreads();
    if (wv == 0 && lane < 16) {
        const float4 a0 = red[0][lane];
        const float4 a1 = red[1][lane];
        const float4 a2 = red[2][lane];
        const float4 a3 = red[3][lane];
        const float4 xl = *(const float4*)(xlin + node * C + lane * 4);
        float4 o;
        o.x = fmaxf(xl.x + a0.x + a1.x + a2.x + a3.x, 0.f);
        o.y = fmaxf(xl.y + a0.y + a1.y + a2.y + a3.y, 0.f);
        o.z = fmaxf(xl.z + a0.z + a1.z + a2.z + a3.z, 0.f);
        o.w = fmaxf(xl.w + a0.w + a1.w + a2.w + a3.w, 0.f);
        *(float4*)(out + node * C + lane * 4) = o;
    }
}

extern "C" void kernel_launch(void* const* d_in, const int* in_sizes, int n_in,
                              void* d_out, int out_size, void* d_ws, size_t ws_size,
                              hipStream_t stream)
{
    const float* x          = (const float*)d_in[0];
    const int*   lower_idx  = (const int*)d_in[1];
    const float* lower_vals = (const float*)d_in[2];
    const int*   upper_idx  = (const int*)d_in[3];
    const float* upper_vals = (const float*)d_in[4];
    const float* w_lower    = (const float*)d_in[5];
    const float* a_lower    = (const float*)d_in[6];
    const float* w_upper    = (const float*)d_in[7];
    const float* a_upper    = (const float*)d_in[8];
    const float* w_lin      = (const float*)d_in[9];

    float* out = (float*)d_out;
    char* ws = (char*)d_ws;

    // ---- workspace layout (~66 MB) ----
    const size_t NC_F = (size_t)N_NODES * C * sizeof(float);          // 12.8 MB
    const size_t NC_H = (size_t)N_NODES * C * sizeof(unsigned short); // 6.4 MB
    unsigned short* xm_l = (unsigned short*)ws;  ws += NC_H;
    unsigned short* xm_u = (unsigned short*)ws;  ws += NC_H;
    float* xlin = (float*)ws;                 ws += NC_F;
    float* ssl  = (float*)ws;                 ws += N_NODES * sizeof(float);
    float* stl  = (float*)ws;                 ws += N_NODES * sizeof(float);
    float* ssu  = (float*)ws;                 ws += N_NODES * sizeof(float);
    float* stu  = (float*)ws;                 ws += N_NODES * sizeof(float);
    int* cnt    = (int*)ws;                   ws += DEG_SZ * sizeof(int);       // 1.6 MB
    unsigned* rec = (unsigned*)ws;            ws += (size_t)DEG_SZ * CAP * sizeof(unsigned); // 38.4 MB

    // K1: precompute + attention scalars + cnt zeroing
    pre_kernel<<<NPRE, 256, 0, stream>>>(
        x, w_lower, a_lower, w_upper, a_upper, w_lin,
        xm_l, xm_u, xlin, ssl, stl, ssu, stu, cnt);

    // K2: direct-bucket fill (single edge pass, no hist/scan)
    fill_kernel<<<NEDGE_B, 256, 0, stream>>>(
        lower_idx, lower_vals, ssl, stl,
        upper_idx, upper_vals, ssu, stu,
        cnt, rec);

    // K3: gather + skip + relu
    gather_kernel<<<N_NODES, 256, 0, stream>>>(
        xlin, cnt, rec, xm_l, xm_u, out);
}

// Round 10
// 259.767 us; speedup vs baseline: 2.1219x; 1.1490x over previous
//
#include <hip/hip_runtime.h>
#include <hip/hip_bf16.h>
#include <math.h>

#define N_NODES 50000
#define N_EDGES 800000
#define C 64
#define EPS_F 1.000001f
#define TWO_N (2 * N_NODES)

// Direct buckets: bin = [p][conv][node]; slab = CAP*4B = 64 B = one cache
// line (CAP=16). p = edge-block & 3 aligned with round-robin XCD dispatch ->
// slab writers stay on a fixed XCD pair (round-3 lesson). deg ~ Poisson(4):
// P(bin > 16) ~ 1e-6 -> expected overflow records ~0.5; exact handling via a
// small global overflow list that gather scans (usually empty).
#define NPART 4
#define DEG_SZ (NPART * TWO_N)     // 400000 bins
#define CAP 16                     // 64-B slab; rec = 25.6 MB
#define OMAX 2048                  // overflow list capacity

#define NPRE ((N_NODES + 31) / 32)   // 1563 blocks, 32 rows each
// Fused K1 geometry: groups of 8 blocks (one XCD round-robin sweep); group
// role by (b>>3)%5: 4 fill-groups : 1 pre-group. This keeps fill's p = b&3
// consistent with XCD = b%8 (cohort-aligned slab writes).
#define NGRP8 980
#define NK1 (NGRP8 * 8)              // 7840 blocks: 6272 fill + 1568 pre

// float <-> bf16 bits (round-to-nearest-even)
__device__ __forceinline__ unsigned short f2bf(float f) {
    unsigned u = __float_as_uint(f);
    return (unsigned short)((u + 0x7FFFu + ((u >> 16) & 1u)) >> 16);
}
__device__ __forceinline__ float bf2f(unsigned short b) {
    return __uint_as_float(((unsigned)b) << 16);
}

// ---------------------------------------------------------------------------
// Kernel 0: attention scalars via the wa-trick + zero cnt[] (incl. ocnt).
//   s_src = xm @ a_src = (x @ W) @ a_src = x @ (W @ a_src)
// Each block redundantly computes the four 64-vectors W@a into LDS (16K MACs,
// trivial), then 4 waves x 8 rows: s values from coalesced x reads.
// ---------------------------------------------------------------------------
__global__ __launch_bounds__(256) void s_kernel(
    const float* __restrict__ x,
    const float* __restrict__ w_l, const float* __restrict__ a_l,
    const float* __restrict__ w_u, const float* __restrict__ a_u,
    float* __restrict__ ssl, float* __restrict__ stl,
    float* __restrict__ ssu, float* __restrict__ stu,
    int* __restrict__ cnt)
{
    const int b = blockIdx.x;
    const int t = threadIdx.x;

    // fused cnt zeroing: 1563*256 = 400128 >= DEG_SZ+1 (ocnt at cnt[DEG_SZ])
    const int gz = b * 256 + t;
    if (gz <= DEG_SZ) cnt[gz] = 0;

    __shared__ float wa[4 * C];      // [l_src | l_tgt | u_src | u_tgt]
    {
        const int v = t >> 6;        // which vector
        const int k = t & 63;        // input-channel index
        const float* __restrict__ w = (v < 2) ? w_l : w_u;
        const float* __restrict__ a = (v < 2) ? a_l : a_u;
        const int ao = (v & 1) * C;
        float acc = 0.f;
#pragma unroll 16
        for (int o = 0; o < C; ++o)
            acc = fmaf(w[k * C + o], a[ao + o], acc);
        wa[v * C + k] = acc;
    }
    __syncthreads();

    const int lane = t & 63;
    const int wv = t >> 6;
    const int row0 = b * 32 + wv * 8;
    if (row0 >= N_NODES) return;

    const float wls = wa[lane], wlt = wa[C + lane];
    const float wus = wa[2 * C + lane], wut = wa[3 * C + lane];

#pragma unroll
    for (int r = 0; r < 8; ++r) {
        const int row = row0 + r;
        if (row >= N_NODES) break;
        const float xv = x[row * C + lane];
        float psl = xv * wls, ptl = xv * wlt;
        float psu = xv * wus, ptu = xv * wut;
#pragma unroll
        for (int o = 32; o >= 1; o >>= 1) {
            psl += __shfl_xor(psl, o);
            ptl += __shfl_xor(ptl, o);
            psu += __shfl_xor(psu, o);
            ptu += __shfl_xor(ptu, o);
        }
        if (lane == 0) {
            ssl[row] = psl; stl[row] = ptl;
            ssu[row] = psu; stu[row] = ptu;
        }
    }
}

// ---------------------------------------------------------------------------
// Kernel 1 (fused): GEMM precompute + direct-bucket fill, role-split by
// (b>>3)%5 with NO grid barrier (round-7 lesson: barriers + mixed-parallelism
// phases lose; round-8 lesson: barrier-free role fusion wins).
// Pre role: 8 rows/wave, wave-uniform row ptrs -> scalar x loads; weights via
// L1/L2-cached vector loads (no LDS -> fill occupancy unthrottled).
// Fill role: alpha = elu(s_src[j]+s_tgt[i])*val; rank = atomicAdd(cnt[bin]);
// rec[bin*CAP+rank] = {j:16|bf16(alpha)}; overflow -> global list.
// ---------------------------------------------------------------------------
__global__ __launch_bounds__(256) void gemm_fill_kernel(
    const float* __restrict__ x,
    const float* __restrict__ w_l, const float* __restrict__ w_u,
    const float* __restrict__ w_lin,
    const int* __restrict__ lidx, const float* __restrict__ lval,
    const int* __restrict__ uidx, const float* __restrict__ uval,
    const float* __restrict__ ssl, const float* __restrict__ stl,
    const float* __restrict__ ssu, const float* __restrict__ stu,
    unsigned short* __restrict__ xm_l, unsigned short* __restrict__ xm_u,
    float* __restrict__ xlin,
    int* __restrict__ cnt, unsigned* __restrict__ rec, int2* __restrict__ ovf)
{
    const int b = blockIdx.x, t = threadIdx.x;
    const int g8 = b >> 3, b7 = b & 7;
    const int q = g8 / 5, r5 = g8 % 5;

    if (r5 != 4) {
        // ---- fill role: edge-chunk h; p = b&3 (XCD-cohort aligned) ----
        const int h = (q * 4 + r5) * 8 + b7;
        const int g = h * 256 + t;
        if (g >= 2 * N_EDGES) return;
        const int p = b & (NPART - 1);

        int bin, j;
        float s, v;
        if (g < N_EDGES) {
            const int i = lidx[g];
            j = lidx[N_EDGES + g];
            v = lval[g];
            s = ssl[j] + stl[i];
            bin = p * TWO_N + i;
        } else {
            const int e = g - N_EDGES;
            const int i = uidx[e];
            j = uidx[N_EDGES + e];
            v = uval[e];
            s = ssu[j] + stu[i];
            bin = p * TWO_N + N_NODES + i;
        }
        s = (s > 0.f) ? s : expm1f(s);
        const unsigned packed = ((unsigned)j << 16) | (unsigned)f2bf(s * v);
        const int rank = atomicAdd(&cnt[bin], 1);
        if (rank < CAP) {
            rec[(size_t)bin * CAP + rank] = packed;
        } else {
            const int oi = atomicAdd(&cnt[DEG_SZ], 1);
            if (oi < OMAX) ovf[oi] = make_int2(bin, (int)packed);
        }
        return;
    }

    // ---- pre role: rows pid*32 .. +31 ----
    const int pid = q * 8 + b7;
    const int lane = t & 63;
    const int wvu = __builtin_amdgcn_readfirstlane(t >> 6);
    const int row0 = pid * 32 + wvu * 8;
    if (row0 >= N_NODES) return;

    const float* xr[8];
#pragma unroll
    for (int r = 0; r < 8; ++r) {
        int rr = row0 + r;
        if (rr >= N_NODES) rr = N_NODES - 1;
        xr[r] = x + (size_t)rr * C;
    }

    float acc_l[8] = {0,0,0,0,0,0,0,0};
    float acc_u[8] = {0,0,0,0,0,0,0,0};
    float acc_n[8] = {0,0,0,0,0,0,0,0};

#pragma unroll 1
    for (int kc = 0; kc < C; kc += 4) {
#pragma unroll
        for (int kk = 0; kk < 4; ++kk) {
            const int k = kc + kk;
            const float wl = w_l[k * C + lane];     // L1/L2-cached, coalesced
            const float wu = w_u[k * C + lane];
            const float wn = w_lin[k * C + lane];
#pragma unroll
            for (int r = 0; r < 8; ++r) {
                const float xk = xr[r][k];          // wave-uniform -> scalar
                acc_l[r] = fmaf(xk, wl, acc_l[r]);
                acc_u[r] = fmaf(xk, wu, acc_u[r]);
                acc_n[r] = fmaf(xk, wn, acc_n[r]);
            }
        }
    }

#pragma unroll
    for (int r = 0; r < 8; ++r) {
        const int row = row0 + r;
        if (row < N_NODES) {
            xm_l[row * C + lane] = f2bf(acc_l[r]);
            xm_u[row * C + lane] = f2bf(acc_u[r]);
            xlin[row * C + lane] = acc_n[r] * EPS_F;
        }
    }
}

// ---------------------------------------------------------------------------
// Kernel 2: gather + fuse. One BLOCK per node; wave w: conv = w>>1, its two
// partitions' bins walked INTERLEAVED (2 rec + 2 row loads in flight).
// sub = lane>>4 picks 1 of 4 sequential records/chunk; cg = lane&15 picks 4
// channels (ushort4). Tail: scan the (usually empty) overflow list.
// ---------------------------------------------------------------------------
__global__ __launch_bounds__(256) void gather_kernel(
    const float* __restrict__ xlin,
    const int* __restrict__ cnt, const unsigned* __restrict__ rec,
    const int2* __restrict__ ovf,
    const unsigned short* __restrict__ xm_l, const unsigned short* __restrict__ xm_u,
    float* __restrict__ out)
{
    const int node = blockIdx.x;
    const int wv = threadIdx.x >> 6;
    const int lane = threadIdx.x & 63;
    const int conv = wv >> 1;
    const int pbase = (wv & 1) * 2;
    const unsigned short* __restrict__ xm = conv ? xm_u : xm_l;
    const int sub = lane >> 4;
    const int cg = lane & 15;

    // prefetch skip branch early (wave 0)
    float4 xl = make_float4(0.f, 0.f, 0.f, 0.f);
    if (wv == 0 && lane < 16) xl = *(const float4*)(xlin + node * C + lane * 4);

    const int bin0 = (pbase + 0) * TWO_N + conv * N_NODES + node;
    const int bin1 = (pbase + 1) * TWO_N + conv * N_NODES + node;
    const int len0 = min(cnt[bin0], CAP);
    const int len1 = min(cnt[bin1], CAP);
    const unsigned* __restrict__ rb0 = rec + (size_t)bin0 * CAP;
    const unsigned* __restrict__ rb1 = rec + (size_t)bin1 * CAP;

    float4 acc = make_float4(0.f, 0.f, 0.f, 0.f);
    int k0 = 0, k1 = 0;
    while ((k0 < len0) | (k1 < len1)) {
        const int i0 = k0 + sub, i1 = k1 + sub;
        const bool a0 = i0 < len0, a1 = i1 < len1;
        const unsigned rw0 = rb0[a0 ? i0 : 0];
        const unsigned rw1 = rb1[a1 ? i1 : 0];
        const int j0 = (int)(rw0 >> 16), j1 = (int)(rw1 >> 16);
        const float w0 = a0 ? bf2f((unsigned short)(rw0 & 0xFFFFu)) : 0.f;
        const float w1 = a1 ? bf2f((unsigned short)(rw1 & 0xFFFFu)) : 0.f;
        const ushort4 r0 = *(const ushort4*)(xm + j0 * C + cg * 4);
        const ushort4 r1 = *(const ushort4*)(xm + j1 * C + cg * 4);
        acc.x = fmaf(w0, bf2f(r0.x), acc.x);
        acc.y = fmaf(w0, bf2f(r0.y), acc.y);
        acc.z = fmaf(w0, bf2f(r0.z), acc.z);
        acc.w = fmaf(w0, bf2f(r0.w), acc.w);
        acc.x = fmaf(w1, bf2f(r1.x), acc.x);
        acc.y = fmaf(w1, bf2f(r1.y), acc.y);
        acc.z = fmaf(w1, bf2f(r1.z), acc.z);
        acc.w = fmaf(w1, bf2f(r1.w), acc.w);
        k0 += (k0 < len0) ? 4 : 0;
        k1 += (k1 < len1) ? 4 : 0;
    }

    // overflow tail (expected ~0 entries; exact correctness for CAP spills)
    const int oc = min(cnt[DEG_SZ], OMAX);
    for (int u = 0; u < oc; ++u) {
        const int2 e = ovf[u];
        if (e.x == bin0 || e.x == bin1) {
            const unsigned rw = (unsigned)e.y;
            const int j = (int)(rw >> 16);
            const float w = (sub == 0) ? bf2f((unsigned short)(rw & 0xFFFFu)) : 0.f;
            const ushort4 r0 = *(const ushort4*)(xm + j * C + cg * 4);
            acc.x = fmaf(w, bf2f(r0.x), acc.x);
            acc.y = fmaf(w, bf2f(r0.y), acc.y);
            acc.z = fmaf(w, bf2f(r0.z), acc.z);
            acc.w = fmaf(w, bf2f(r0.w), acc.w);
        }
    }

    acc.x += __shfl_xor(acc.x, 16);
    acc.y += __shfl_xor(acc.y, 16);
    acc.z += __shfl_xor(acc.z, 16);
    acc.w += __shfl_xor(acc.w, 16);
    acc.x += __shfl_xor(acc.x, 32);
    acc.y += __shfl_xor(acc.y, 32);
    acc.z += __shfl_xor(acc.z, 32);
    acc.w += __shfl_xor(acc.w, 32);

    __shared__ float4 red[4][16];
    if (lane < 16) red[wv][lane] = acc;
    __syncthreads();
    if (wv == 0 && lane < 16) {
        const float4 a0 = red[0][lane];
        const float4 a1 = red[1][lane];
        const float4 a2 = red[2][lane];
        const float4 a3 = red[3][lane];
        float4 o;
        o.x = fmaxf(xl.x + a0.x + a1.x + a2.x + a3.x, 0.f);
        o.y = fmaxf(xl.y + a0.y + a1.y + a2.y + a3.y, 0.f);
        o.z = fmaxf(xl.z + a0.z + a1.z + a2.z + a3.z, 0.f);
        o.w = fmaxf(xl.w + a0.w + a1.w + a2.w + a3.w, 0.f);
        *(float4*)(out + node * C + lane * 4) = o;
    }
}

extern "C" void kernel_launch(void* const* d_in, const int* in_sizes, int n_in,
                              void* d_out, int out_size, void* d_ws, size_t ws_size,
                              hipStream_t stream)
{
    const float* x          = (const float*)d_in[0];
    const int*   lower_idx  = (const int*)d_in[1];
    const float* lower_vals = (const float*)d_in[2];
    const int*   upper_idx  = (const int*)d_in[3];
    const float* upper_vals = (const float*)d_in[4];
    const float* w_lower    = (const float*)d_in[5];
    const float* a_lower    = (const float*)d_in[6];
    const float* w_upper    = (const float*)d_in[7];
    const float* a_upper    = (const float*)d_in[8];
    const float* w_lin      = (const float*)d_in[9];

    float* out = (float*)d_out;
    char* ws = (char*)d_ws;

    // ---- workspace layout (~54 MB) ----
    const size_t NC_F = (size_t)N_NODES * C * sizeof(float);          // 12.8 MB
    const size_t NC_H = (size_t)N_NODES * C * sizeof(unsigned short); // 6.4 MB
    unsigned short* xm_l = (unsigned short*)ws;  ws += NC_H;
    unsigned short* xm_u = (unsigned short*)ws;  ws += NC_H;
    float* xlin = (float*)ws;                 ws += NC_F;
    float* ssl  = (float*)ws;                 ws += N_NODES * sizeof(float);
    float* stl  = (float*)ws;                 ws += N_NODES * sizeof(float);
    float* ssu  = (float*)ws;                 ws += N_NODES * sizeof(float);
    float* stu  = (float*)ws;                 ws += N_NODES * sizeof(float);
    int* cnt    = (int*)ws;                   ws += (DEG_SZ + 16) * sizeof(int); // +ocnt
    int2* ovf   = (int2*)ws;                  ws += OMAX * sizeof(int2);
    unsigned* rec = (unsigned*)ws;            ws += (size_t)DEG_SZ * CAP * sizeof(unsigned); // 25.6 MB

    // K0: attention scalars (wa-trick) + cnt/ocnt zeroing
    s_kernel<<<NPRE, 256, 0, stream>>>(
        x, w_lower, a_lower, w_upper, a_upper,
        ssl, stl, ssu, stu, cnt);

    // K1: fused GEMM precompute + direct-bucket fill
    gemm_fill_kernel<<<NK1, 256, 0, stream>>>(
        x, w_lower, w_upper, w_lin,
        lower_idx, lower_vals, upper_idx, upper_vals,
        ssl, stl, ssu, stu,
        xm_l, xm_u, xlin, cnt, rec, ovf);

    // K2: gather + skip + relu
    gather_kernel<<<N_NODES, 256, 0, stream>>>(
        xlin, cnt, rec, ovf, xm_l, xm_u, out);
}

// Round 11
// 257.814 us; speedup vs baseline: 2.1380x; 1.0076x over previous
//
#include <hip/hip_runtime.h>
#include <hip/hip_bf16.h>
#include <math.h>

#define N_NODES 50000
#define N_EDGES 800000
#define C 64
#define EPS_F 1.000001f
#define TWO_N (2 * N_NODES)

// Direct buckets: bin = [p][conv][node]; slab = CAP*4B = 32 B (CAP=8).
// NPART=8 with p = blockIdx&7 == XCD id -> each partition's 3.2 MB rec region
// is written by exactly ONE XCD and fits its 4 MiB L2: slab lines stay
// resident until complete and evict once (round-10 lesson: NPART=4 regions of
// 6.4 MB across 2 XCDs thrashed -> 126 MB WRITE for ~33 MB useful).
// Overflow (bin deg ~ Poisson(2), P(>8) ~ 7e-4): cascade into the next
// partition's bin for the same node — gather sums all partitions, so this is
// exact; total capacity 64 slots/node/conv vs max degree ~40.
#define NPART 8
#define DEG_SZ (NPART * TWO_N)     // 800000 bins
#define CAP 8                      // 32-B slab; rec = 25.6 MB
#define NSLICE (N_NODES / 8)       // 6250: nodes per XCD slice in gather

#define NPRE ((N_NODES + 31) / 32)   // 1563 blocks, 32 rows each
// Fused K1 geometry: groups of 8 blocks (one XCD round-robin sweep); group
// role by (b>>3)%5: 4 fill-groups : 1 pre-group. Keeps fill's p = b&7 == XCD.
#define NGRP8 980
#define NK1 (NGRP8 * 8)              // 7840 blocks: 6272 fill + 1568 pre

typedef __attribute__((ext_vector_type(8))) unsigned short u16x8;

// float <-> bf16 bits (round-to-nearest-even)
__device__ __forceinline__ unsigned short f2bf(float f) {
    unsigned u = __float_as_uint(f);
    return (unsigned short)((u + 0x7FFFu + ((u >> 16) & 1u)) >> 16);
}
__device__ __forceinline__ float bf2f(unsigned short b) {
    return __uint_as_float(((unsigned)b) << 16);
}

// ---------------------------------------------------------------------------
// Kernel 0: attention scalars via the wa-trick + zero cnt[] (int2 covers
// 800016 ints with 400128 threads).
//   s_src = (x @ W) @ a_src = x @ (W @ a_src)
// ---------------------------------------------------------------------------
__global__ __launch_bounds__(256) void s_kernel(
    const float* __restrict__ x,
    const float* __restrict__ w_l, const float* __restrict__ a_l,
    const float* __restrict__ w_u, const float* __restrict__ a_u,
    float* __restrict__ ssl, float* __restrict__ stl,
    float* __restrict__ ssu, float* __restrict__ stu,
    int* __restrict__ cnt)
{
    const int b = blockIdx.x;
    const int t = threadIdx.x;

    // fused cnt zeroing: 400128 int2 writes cover DEG_SZ+16 ints
    const int gz = b * 256 + t;
    if (gz < (DEG_SZ + 16) / 2) ((int2*)cnt)[gz] = make_int2(0, 0);

    __shared__ float wa[4 * C];      // [l_src | l_tgt | u_src | u_tgt]
    {
        const int v = t >> 6;
        const int k = t & 63;
        const float* __restrict__ w = (v < 2) ? w_l : w_u;
        const float* __restrict__ a = (v < 2) ? a_l : a_u;
        const int ao = (v & 1) * C;
        float acc = 0.f;
#pragma unroll 16
        for (int o = 0; o < C; ++o)
            acc = fmaf(w[k * C + o], a[ao + o], acc);
        wa[v * C + k] = acc;
    }
    __syncthreads();

    const int lane = t & 63;
    const int wv = t >> 6;
    const int row0 = b * 32 + wv * 8;
    if (row0 >= N_NODES) return;

    const float wls = wa[lane], wlt = wa[C + lane];
    const float wus = wa[2 * C + lane], wut = wa[3 * C + lane];

#pragma unroll
    for (int r = 0; r < 8; ++r) {
        const int row = row0 + r;
        if (row >= N_NODES) break;
        const float xv = x[row * C + lane];
        float psl = xv * wls, ptl = xv * wlt;
        float psu = xv * wus, ptu = xv * wut;
#pragma unroll
        for (int o = 32; o >= 1; o >>= 1) {
            psl += __shfl_xor(psl, o);
            ptl += __shfl_xor(ptl, o);
            psu += __shfl_xor(psu, o);
            ptu += __shfl_xor(ptu, o);
        }
        if (lane == 0) {
            ssl[row] = psl; stl[row] = ptl;
            ssu[row] = psu; stu[row] = ptu;
        }
    }
}

// ---------------------------------------------------------------------------
// Kernel 1 (fused): GEMM precompute + direct-bucket fill, role-split with NO
// grid barrier. Fill: alpha = elu(s_src[j]+s_tgt[i])*val; claim a slot in
// bin (p0, conv, i); on full bin cascade p0+1, p0+2, ... (exact; see top).
// Pre: 8 rows/wave, wave-uniform row ptrs -> scalar x loads; weights via
// cached vector loads (no LDS).
// ---------------------------------------------------------------------------
__global__ __launch_bounds__(256) void gemm_fill_kernel(
    const float* __restrict__ x,
    const float* __restrict__ w_l, const float* __restrict__ w_u,
    const float* __restrict__ w_lin,
    const int* __restrict__ lidx, const float* __restrict__ lval,
    const int* __restrict__ uidx, const float* __restrict__ uval,
    const float* __restrict__ ssl, const float* __restrict__ stl,
    const float* __restrict__ ssu, const float* __restrict__ stu,
    unsigned short* __restrict__ xm_l, unsigned short* __restrict__ xm_u,
    float* __restrict__ xlin,
    int* __restrict__ cnt, unsigned* __restrict__ rec)
{
    const int b = blockIdx.x, t = threadIdx.x;
    const int g8 = b >> 3, b7 = b & 7;
    const int q = g8 / 5, r5 = g8 % 5;

    if (r5 != 4) {
        // ---- fill role: edge-chunk h; p0 = b&7 == XCD ----
        const int h = (q * 4 + r5) * 8 + b7;
        const int g = h * 256 + t;
        if (g >= 2 * N_EDGES) return;
        const int p0 = b7;

        int base, j;
        float s, v;
        if (g < N_EDGES) {
            const int i = lidx[g];
            j = lidx[N_EDGES + g];
            v = lval[g];
            s = ssl[j] + stl[i];
            base = i;                      // conv 0
        } else {
            const int e = g - N_EDGES;
            const int i = uidx[e];
            j = uidx[N_EDGES + e];
            v = uval[e];
            s = ssu[j] + stu[i];
            base = N_NODES + i;            // conv 1
        }
        s = (s > 0.f) ? s : expm1f(s);
        const unsigned packed = ((unsigned)j << 16) | (unsigned)f2bf(s * v);
#pragma unroll 1
        for (int trial = 0; trial < NPART; ++trial) {
            const int bin = (((p0 + trial) & (NPART - 1)) * TWO_N) + base;
            const int rank = atomicAdd(&cnt[bin], 1);
            if (rank < CAP) {
                rec[(size_t)bin * CAP + rank] = packed;
                break;
            }
        }
        return;
    }

    // ---- pre role: rows pid*32 .. +31 ----
    const int pid = q * 8 + b7;
    const int lane = t & 63;
    const int wvu = __builtin_amdgcn_readfirstlane(t >> 6);
    const int row0 = pid * 32 + wvu * 8;
    if (row0 >= N_NODES) return;

    const float* xr[8];
#pragma unroll
    for (int r = 0; r < 8; ++r) {
        int rr = row0 + r;
        if (rr >= N_NODES) rr = N_NODES - 1;
        xr[r] = x + (size_t)rr * C;
    }

    float acc_l[8] = {0,0,0,0,0,0,0,0};
    float acc_u[8] = {0,0,0,0,0,0,0,0};
    float acc_n[8] = {0,0,0,0,0,0,0,0};

#pragma unroll 1
    for (int kc = 0; kc < C; kc += 4) {
#pragma unroll
        for (int kk = 0; kk < 4; ++kk) {
            const int k = kc + kk;
            const float wl = w_l[k * C + lane];
            const float wu = w_u[k * C + lane];
            const float wn = w_lin[k * C + lane];
#pragma unroll
            for (int r = 0; r < 8; ++r) {
                const float xk = xr[r][k];      // wave-uniform -> scalar load
                acc_l[r] = fmaf(xk, wl, acc_l[r]);
                acc_u[r] = fmaf(xk, wu, acc_u[r]);
                acc_n[r] = fmaf(xk, wn, acc_n[r]);
            }
        }
    }

#pragma unroll
    for (int r = 0; r < 8; ++r) {
        const int row = row0 + r;
        if (row < N_NODES) {
            xm_l[row * C + lane] = f2bf(acc_l[r]);
            xm_u[row * C + lane] = f2bf(acc_u[r]);
            xlin[row * C + lane] = acc_n[r] * EPS_F;
        }
    }
}

// ---------------------------------------------------------------------------
// Kernel 2: gather + fuse. One BLOCK per node, node XCD-swizzled so
// consecutive nodes share an XCD (rec/cnt/xlin/out line reuse in L2).
// Wave w: conv = w>>1, partitions (w&1)*4..+3. Per bin: ONE fixed iteration —
// sub = lane>>3 picks the record slot (covers the whole CAP=8 slab),
// cg = lane&7 picks 8 channels (16 B ushort8 row load). No loop-carried
// dependence; inactive slots masked to row 0 (L1-hot).
// ---------------------------------------------------------------------------
__global__ __launch_bounds__(256) void gather_kernel(
    const float* __restrict__ xlin,
    const int* __restrict__ cnt, const unsigned* __restrict__ rec,
    const unsigned short* __restrict__ xm_l, const unsigned short* __restrict__ xm_u,
    float* __restrict__ out)
{
    const int braw = blockIdx.x;
    const int node = (braw >> 3) + (braw & 7) * NSLICE;   // XCD slice
    const int wv = threadIdx.x >> 6;
    const int lane = threadIdx.x & 63;
    const int conv = wv >> 1;
    const int pbase = (wv & 1) * 4;
    const unsigned short* __restrict__ xm = conv ? xm_u : xm_l;
    const int sub = lane >> 3;      // record slot 0..7
    const int cg = lane & 7;        // channel group: channels cg*8 .. +7

    float acc[8] = {0.f,0.f,0.f,0.f,0.f,0.f,0.f,0.f};

#pragma unroll
    for (int s2 = 0; s2 < 4; ++s2) {
        const int bin = (pbase + s2) * TWO_N + conv * N_NODES + node;
        const int len = min(cnt[bin], CAP);
        const unsigned rw = rec[(size_t)bin * CAP + sub];
        const bool act = sub < len;
        const int j = act ? (int)(rw >> 16) : 0;
        const float w = act ? bf2f((unsigned short)(rw & 0xFFFFu)) : 0.f;
        const u16x8 row = *(const u16x8*)(xm + j * C + cg * 8);
#pragma unroll
        for (int c = 0; c < 8; ++c)
            acc[c] = fmaf(w, bf2f(row[c]), acc[c]);
    }

    // reduce across the 8 record slots (lane bits 3..5)
#pragma unroll
    for (int o = 8; o <= 32; o <<= 1)
#pragma unroll
        for (int c = 0; c < 8; ++c)
            acc[c] += __shfl_xor(acc[c], o);

    __shared__ float red[4][C];
    if (lane < 8) {
#pragma unroll
        for (int c = 0; c < 8; ++c) red[wv][lane * 8 + c] = acc[c];
    }
    __syncthreads();
    if (wv == 0) {
        const float sum = xlin[node * C + lane]
                        + red[0][lane] + red[1][lane] + red[2][lane] + red[3][lane];
        out[node * C + lane] = fmaxf(sum, 0.f);
    }
}

extern "C" void kernel_launch(void* const* d_in, const int* in_sizes, int n_in,
                              void* d_out, int out_size, void* d_ws, size_t ws_size,
                              hipStream_t stream)
{
    const float* x          = (const float*)d_in[0];
    const int*   lower_idx  = (const int*)d_in[1];
    const float* lower_vals = (const float*)d_in[2];
    const int*   upper_idx  = (const int*)d_in[3];
    const float* upper_vals = (const float*)d_in[4];
    const float* w_lower    = (const float*)d_in[5];
    const float* a_lower    = (const float*)d_in[6];
    const float* w_upper    = (const float*)d_in[7];
    const float* a_upper    = (const float*)d_in[8];
    const float* w_lin      = (const float*)d_in[9];

    float* out = (float*)d_out;
    char* ws = (char*)d_ws;

    // ---- workspace layout (~55 MB) ----
    const size_t NC_F = (size_t)N_NODES * C * sizeof(float);          // 12.8 MB
    const size_t NC_H = (size_t)N_NODES * C * sizeof(unsigned short); // 6.4 MB
    unsigned short* xm_l = (unsigned short*)ws;  ws += NC_H;
    unsigned short* xm_u = (unsigned short*)ws;  ws += NC_H;
    float* xlin = (float*)ws;                 ws += NC_F;
    float* ssl  = (float*)ws;                 ws += N_NODES * sizeof(float);
    float* stl  = (float*)ws;                 ws += N_NODES * sizeof(float);
    float* ssu  = (float*)ws;                 ws += N_NODES * sizeof(float);
    float* stu  = (float*)ws;                 ws += N_NODES * sizeof(float);
    int* cnt    = (int*)ws;                   ws += (DEG_SZ + 16) * sizeof(int); // 3.2 MB
    unsigned* rec = (unsigned*)ws;            ws += (size_t)DEG_SZ * CAP * sizeof(unsigned); // 25.6 MB

    // K0: attention scalars (wa-trick) + cnt zeroing
    s_kernel<<<NPRE, 256, 0, stream>>>(
        x, w_lower, a_lower, w_upper, a_upper,
        ssl, stl, ssu, stu, cnt);

    // K1: fused GEMM precompute + direct-bucket fill (cascade overflow)
    gemm_fill_kernel<<<NK1, 256, 0, stream>>>(
        x, w_lower, w_upper, w_lin,
        lower_idx, lower_vals, upper_idx, upper_vals,
        ssl, stl, ssu, stu,
        xm_l, xm_u, xlin, cnt, rec);

    // K2: gather + skip + relu
    gather_kernel<<<N_NODES, 256, 0, stream>>>(
        xlin, cnt, rec, xm_l, xm_u, out);
}